// Round 5
// baseline (396.563 us; speedup 1.0000x reference)
//
#include <hip/hip_runtime.h>

typedef unsigned short u16;
typedef __attribute__((ext_vector_type(8))) __bf16 bf16x8;
typedef __attribute__((ext_vector_type(8))) short short8;
typedef __attribute__((ext_vector_type(4))) float floatx4;

__device__ __forceinline__ u16 f2bf(float f){
  unsigned int x = __float_as_uint(f);
  unsigned int r = (x + 0x7fffu + ((x >> 16) & 1u)) >> 16;  // RTNE
  return (u16)r;
}

// async 16B global->LDS copy; lds base must be wave-uniform (HW: base + lane*16)
#define GLL(g, l) __builtin_amdgcn_global_load_lds( \
    (const __attribute__((address_space(1))) void*)(g), \
    (__attribute__((address_space(3))) void*)(l), 16, 0, 0)

// ============================ PREP PASS =====================================
// blocks 0..1023: x[b][ci][t][y][zw] fp32 -> xp[b][t][y][zw][ci] bf16,
//                 with 16B chunks XOR-placed: chunk oct stored at (oct^(row&7)).
// blocks 1024..2319: weight fp32 -> wp[tap][kc][co][ci32] bf16 (coalesced reads).
__global__ void prep_kernel(const float* __restrict__ x, const float* __restrict__ w,
                            u16* __restrict__ xp, u16* __restrict__ wp){
  const int bx = blockIdx.x;
  const int tid = threadIdx.x;
  if (bx < 1024){
    const int y = bx & 15, t = (bx >> 4) & 15, b = bx >> 8;
    const float* src = x + (size_t)b*64*65536 + t*4096 + y*256 + tid;  // + ci*65536
    u16* dst = xp + (size_t)bx*16384 + tid*64;                          // row = tid
#pragma unroll
    for (int oct = 0; oct < 8; ++oct){
      float v[8];
#pragma unroll
      for (int j = 0; j < 8; ++j)
        v[j] = src[(oct*8 + j)*65536];
      short8 vv;
#pragma unroll
      for (int j = 0; j < 8; ++j) vv[j] = (short)f2bf(v[j]);
      *(short8*)(dst + ((oct ^ (tid & 7))*8)) = vv;
    }
  } else {
    int idx = (bx - 1024)*256 + tid;   // linear over w input (coalesced)
    if (idx < 81*64*64){
      int r  = idx;
      int dw = r % 3; r /= 3;
      int dz = r % 3; r /= 3;
      int dy = r % 3; r /= 3;
      int ci = r & 63; r >>= 6;
      int co = r & 63; r >>= 6;
      int dt = r;
      int tap = ((dt*3 + dy)*3 + dz)*3 + dw;
      int kc = ci >> 5, ci32 = ci & 31;
      wp[tap*4096 + kc*2048 + co*32 + ci32] = f2bf(w[idx]);
    }
  }
}

// ============================ MAIN KERNEL ===================================
// block = (b,t,y); 4 waves; wave wv owns z-rows wv*4..wv*4+3, all 64 co.
// A (weights) read DIRECTLY from global (L2-resident, 663 KB) into VGPRs with
// a one-group register double-buffer; only the x-plane goes through LDS.
// Barriers: 2 per x-stage (18/block) vs 63 in the LDS-A version.
__global__ __launch_bounds__(256, 3) void conv4d_mfma_v3(
    const u16* __restrict__ xp, const u16* __restrict__ wp,
    const float* __restrict__ bias, float* __restrict__ out)
{
  __shared__ __attribute__((aligned(16))) u16 x_lds[16384];  // [zw][ci], 128B rows, XOR chunks

  const int bx = blockIdx.x;
  const int y = bx & 15, t = (bx >> 4) & 15, b = bx >> 8;
  const int tid  = threadIdx.x;
  const int lane = tid & 63;
  const int wv   = tid >> 6;
  const int wl   = lane & 15;   // B: n (w-pos); A: m (co row within 16-tile)
  const int q    = lane >> 4;   // k-octet selector; D: co = quad*4+reg

  floatx4 acc[4][4];
#pragma unroll
  for (int zi = 0; zi < 4; ++zi)
#pragma unroll
    for (int mi = 0; mi < 4; ++mi)
      acc[zi][mi] = (floatx4)0.0f;

  // lane-fixed part of the A-fragment address; group (tap,kc) adds (tap*2+kc)*2048
  const u16* wbase = wp + wl*32 + q*8;

  // group G = dtdy*18 + g, g = dz*6 + dw*2 + kc; 162 groups total
  auto ldA = [&](int G, bf16x8* af){
    const int dtdy = G / 18, g = G % 18;
    const int dt = dtdy / 3, dy = dtdy % 3;
    const int dz = g / 6, dw = (g % 6) >> 1, kc = g & 1;
    const int tap = ((dt*3 + dy)*3 + dz)*3 + dw;
    const u16* p = wbase + (tap*2 + kc)*2048;
#pragma unroll
    for (int mi = 0; mi < 4; ++mi)
      af[mi] = *(const bf16x8*)(p + mi*512);   // coalesced 1KB global_load_dwordx4
  };

  bf16x8 afc[4], afn[4];
  ldA(0, afc);

  for (int dtdy = 0; dtdy < 9; ++dtdy){
    const int dt = dtdy / 3, dy = dtdy % 3;
    const int tt = (t + dt + 15) & 15;
    const int yy = (y + dy + 15) & 15;
    __syncthreads();   // previous compute done before x_lds overwrite
    {
      const u16* plane = xp + (size_t)(((b*16 + tt)*16) + yy) * 16384;
#pragma unroll
      for (int i = 0; i < 8; ++i)
        GLL(plane + wv*4096 + i*512 + lane*8, x_lds + wv*4096 + i*512);
    }
    __syncthreads();   // drains vmcnt(0): x plane staged (A prefetch also lands)
#pragma unroll
    for (int g = 0; g < 18; ++g){
      const int dz = g / 6, dw = (g % 6) >> 1, kc = g & 1;
      const int G = dtdy*18 + g;
      ldA(G + 1 < 162 ? G + 1 : 161, afn);   // prefetch next group during MFMAs
      const int ww = (wl + dw + 15) & 15;
      const int chunk = ((kc*4 + q) ^ (ww & 7))*8;
#pragma unroll
      for (int zi = 0; zi < 4; ++zi){
        const int zz = (wv*4 + zi + dz + 15) & 15;
        bf16x8 bf = *(const bf16x8*)(x_lds + (zz*16 + ww)*64 + chunk);
#pragma unroll
        for (int mi = 0; mi < 4; ++mi)
          acc[zi][mi] = __builtin_amdgcn_mfma_f32_16x16x32_bf16(afc[mi], bf, acc[zi][mi], 0, 0, 0);
      }
#pragma unroll
      for (int mi = 0; mi < 4; ++mi) afc[mi] = afn[mi];
    }
  }

  // ---- epilogue: bias + fp32 store
  float bvals[4][4];
#pragma unroll
  for (int mi = 0; mi < 4; ++mi)
#pragma unroll
    for (int r = 0; r < 4; ++r)
      bvals[mi][r] = bias[mi*16 + q*4 + r];

  float* ob = out + (size_t)b*64*65536 + t*4096 + y*256 + wl;
#pragma unroll
  for (int zi = 0; zi < 4; ++zi){
    const int z = wv*4 + zi;
#pragma unroll
    for (int mi = 0; mi < 4; ++mi){
#pragma unroll
      for (int r = 0; r < 4; ++r){
        const int co = mi*16 + q*4 + r;   // C/D: row = quad*4 + reg
        ob[(size_t)co*65536 + z*16] = acc[zi][mi][r] + bvals[mi][r];
      }
    }
  }
}

// ===================== FALLBACK (round-2 proven path) =======================
__global__ void repack_w_kernel(const float* __restrict__ w, u16* __restrict__ wp){
  int idx = blockIdx.x * 256 + threadIdx.x;
  if (idx >= 81*64*64) return;
  int cw  = idx & 31;
  int t1  = idx >> 5;
  int co  = t1 & 63; t1 >>= 6;
  int kc  = t1 & 1;  t1 >>= 1;
  int tap = t1;
  int dw = tap % 3, dz = (tap/3) % 3, dy = (tap/9) % 3, dt = tap/27;
  int ci = kc*32 + cw;
  int in_idx = ((((dt*64 + co)*64 + ci)*3 + dy)*3 + dz)*3 + dw;
  wp[idx] = f2bf(w[in_idx]);
}

__global__ __launch_bounds__(256, 2) void conv4d_mfma_kernel(
    const float* __restrict__ x, const u16* __restrict__ wp,
    const float* __restrict__ bias, float* __restrict__ out)
{
  __shared__ __attribute__((aligned(16))) u16 x_lds[256*72];
  __shared__ __attribute__((aligned(16))) u16 a_lds[3*2*64*32];
  const int bx = blockIdx.x;
  const int y = bx & 15, t = (bx >> 4) & 15, b = bx >> 8;
  const int tid  = threadIdx.x;
  const int lane = tid & 63;
  const int wv   = tid >> 6;
  const int wl   = lane & 15;
  const int q    = lane >> 4;
  floatx4 acc[4][4];
#pragma unroll
  for (int zi = 0; zi < 4; ++zi)
#pragma unroll
    for (int mi = 0; mi < 4; ++mi)
      acc[zi][mi] = (floatx4)0.0f;
  const float* xb = x + (size_t)b * 64 * 65536;
  for (int dt = 0; dt < 3; ++dt){
    const int tt = (t + dt + 15) & 15;
    for (int dy = 0; dy < 3; ++dy){
      const int yy = (y + dy + 15) & 15;
      __syncthreads();
      {
        const float* src = xb + tt*4096 + yy*256 + tid;
#pragma unroll
        for (int oct = 0; oct < 8; ++oct){
          float v[8];
#pragma unroll
          for (int j = 0; j < 8; ++j)
            v[j] = src[(size_t)(oct*8 + j) * 65536];
          short8 vv;
#pragma unroll
          for (int j = 0; j < 8; ++j) vv[j] = (short)f2bf(v[j]);
          *(short8*)(x_lds + tid*72 + oct*8) = vv;
        }
      }
      for (int dz = 0; dz < 3; ++dz){
        const int tap0 = ((dt*3 + dy)*3 + dz)*3;
        __syncthreads();
        {
          const u16* asrc = wp + (size_t)tap0 * 4096;
#pragma unroll
          for (int i = 0; i < 6; ++i){
            int e = (i*256 + tid) * 8;
            *(short8*)(a_lds + e) = *(const short8*)(asrc + e);
          }
        }
        __syncthreads();
#pragma unroll
        for (int dw = 0; dw < 3; ++dw){
          const int ww = (wl + dw + 15) & 15;
#pragma unroll
          for (int kc = 0; kc < 2; ++kc){
            bf16x8 af[4];
#pragma unroll
            for (int mi = 0; mi < 4; ++mi)
              af[mi] = *(const bf16x8*)(a_lds + ((dw*2 + kc)*64 + mi*16 + wl)*32 + q*8);
#pragma unroll
            for (int zi = 0; zi < 4; ++zi){
              const int zz = (wv*4 + zi + dz + 15) & 15;
              bf16x8 bf = *(const bf16x8*)(x_lds + (zz*16 + ww)*72 + kc*32 + q*8);
#pragma unroll
              for (int mi = 0; mi < 4; ++mi)
                acc[zi][mi] = __builtin_amdgcn_mfma_f32_16x16x32_bf16(af[mi], bf, acc[zi][mi], 0, 0, 0);
            }
          }
        }
      }
    }
  }
  float bvals[4][4];
#pragma unroll
  for (int mi = 0; mi < 4; ++mi)
#pragma unroll
    for (int r = 0; r < 4; ++r)
      bvals[mi][r] = bias[mi*16 + q*4 + r];
  float* ob = out + (size_t)b * 64 * 65536 + t*4096 + y*256 + wl;
#pragma unroll
  for (int zi = 0; zi < 4; ++zi){
    const int z = wv*4 + zi;
#pragma unroll
    for (int mi = 0; mi < 4; ++mi){
#pragma unroll
      for (int r = 0; r < 4; ++r){
        const int co = mi*16 + q*4 + r;
        ob[(size_t)co*65536 + z*16] = acc[zi][mi][r] + bvals[mi][r];
      }
    }
  }
}

extern "C" void kernel_launch(void* const* d_in, const int* in_sizes, int n_in,
                              void* d_out, int out_size, void* d_ws, size_t ws_size,
                              hipStream_t stream) {
  const float* x    = (const float*)d_in[0];
  const float* w    = (const float*)d_in[1];
  const float* bias = (const float*)d_in[2];
  float* out = (float*)d_out;

  const size_t xp_bytes = (size_t)1024 * 16384 * 2;   // 33.55 MB bf16 transposed x
  const size_t wp_bytes = 81*64*64*2;                  // 663.5 KB packed weights
  if (ws_size >= xp_bytes + wp_bytes){
    u16* xp = (u16*)d_ws;
    u16* wp = (u16*)((char*)d_ws + xp_bytes);
    prep_kernel<<<1024 + 1296, 256, 0, stream>>>(x, w, xp, wp);
    conv4d_mfma_v3<<<1024, 256, 0, stream>>>(xp, wp, bias, out);
  } else {
    u16* wp = (u16*)d_ws;
    repack_w_kernel<<<1296, 256, 0, stream>>>(w, wp);
    conv4d_mfma_kernel<<<1024, 256, 0, stream>>>(x, wp, bias, out);
  }
}

// Round 6
// 256.359 us; speedup vs baseline: 1.5469x; 1.5469x over previous
//
#include <hip/hip_runtime.h>

typedef unsigned short u16;
typedef __attribute__((ext_vector_type(8))) __bf16 bf16x8;
typedef __attribute__((ext_vector_type(8))) short short8;
typedef __attribute__((ext_vector_type(4))) float floatx4;

__device__ __forceinline__ u16 f2bf(float f){
  unsigned int x = __float_as_uint(f);
  unsigned int r = (x + 0x7fffu + ((x >> 16) & 1u)) >> 16;  // RTNE
  return (u16)r;
}

// async 16B global->LDS copy; lds base must be wave-uniform (HW: base + lane*16)
#define GLL(g, l) __builtin_amdgcn_global_load_lds( \
    (const __attribute__((address_space(1))) void*)(g), \
    (__attribute__((address_space(3))) void*)(l), 16, 0, 0)

// ============================ PREP PASS =====================================
// blocks 0..1023: x[b][ci][t][y][zw] fp32 -> xp[b][t][y][zw][ci] bf16,
//                 with 16B chunks XOR-placed: chunk oct stored at (oct^(row&7)).
// blocks 1024..2319: weight fp32 -> wp[tap][kc][co][ci32] bf16 (coalesced reads).
__global__ void prep_kernel(const float* __restrict__ x, const float* __restrict__ w,
                            u16* __restrict__ xp, u16* __restrict__ wp){
  const int bx = blockIdx.x;
  const int tid = threadIdx.x;
  if (bx < 1024){
    const int y = bx & 15, t = (bx >> 4) & 15, b = bx >> 8;
    const float* src = x + (size_t)b*64*65536 + t*4096 + y*256 + tid;  // + ci*65536
    u16* dst = xp + (size_t)bx*16384 + tid*64;                          // row = tid
#pragma unroll
    for (int oct = 0; oct < 8; ++oct){
      float v[8];
#pragma unroll
      for (int j = 0; j < 8; ++j)
        v[j] = src[(oct*8 + j)*65536];
      short8 vv;
#pragma unroll
      for (int j = 0; j < 8; ++j) vv[j] = (short)f2bf(v[j]);
      *(short8*)(dst + ((oct ^ (tid & 7))*8)) = vv;
    }
  } else {
    int idx = (bx - 1024)*256 + tid;   // linear over w input (coalesced)
    if (idx < 81*64*64){
      int r  = idx;
      int dw = r % 3; r /= 3;
      int dz = r % 3; r /= 3;
      int dy = r % 3; r /= 3;
      int ci = r & 63; r >>= 6;
      int co = r & 63; r >>= 6;
      int dt = r;
      int tap = ((dt*3 + dy)*3 + dz)*3 + dw;
      int kc = ci >> 5, ci32 = ci & 31;
      wp[tap*4096 + kc*2048 + co*32 + ci32] = f2bf(w[idx]);
    }
  }
}

// ============================ MAIN KERNEL ===================================
// block = (b,t,y) via XCD swizzle; 4 waves; wave wv owns z-rows wv*4..wv*4+3.
// x-plane in single LDS buffer (restaged per (dt,dy)); A-slab (3 taps, 24 KB)
// in DOUBLE-buffered LDS: slab s+1 is GLL-prefetched before computing slab s,
// so the ~480 cyc of MFMAs hides the load latency and barriers find vmcnt
// already drained. 34 barriers/block vs 63 in round 4.
__global__ __launch_bounds__(256, 2) void conv4d_mfma_v4(
    const u16* __restrict__ xp, const u16* __restrict__ wp,
    const float* __restrict__ bias, float* __restrict__ out)
{
  __shared__ __attribute__((aligned(16))) u16 x_lds[16384];     // [zw][ci], XOR chunks
  __shared__ __attribute__((aligned(16))) u16 a_lds[2][12288];  // [dw][kc][co][ci32] x2

  // XCD-aware swizzle: XCD c = bx&7 owns (b = c>>1, y-half = c&1) — its 9x
  // re-reads of xp planes stay in its own L2 (~5 MB working set).
  const int bx = blockIdx.x;
  const int c = bx & 7, j = bx >> 3;
  const int b = c >> 1, t = j >> 3, y = (c & 1)*8 + (j & 7);

  const int tid  = threadIdx.x;
  const int lane = tid & 63;
  const int wv   = tid >> 6;
  const int wl   = lane & 15;   // B: n (w-pos); A: m (co row within 16-tile)
  const int q    = lane >> 4;   // k-octet selector; D: co = quad*4+reg

  floatx4 acc[4][4];
#pragma unroll
  for (int zi = 0; zi < 4; ++zi)
#pragma unroll
    for (int mi = 0; mi < 4; ++mi)
      acc[zi][mi] = (floatx4)0.0f;

  auto stage_x = [&](int dtdy){
    const int dt = dtdy / 3, dy = dtdy % 3;
    const int tt = (t + dt + 15) & 15;
    const int yy = (y + dy + 15) & 15;
    const u16* plane = xp + (size_t)(((b*16 + tt)*16) + yy) * 16384;
#pragma unroll
    for (int i = 0; i < 8; ++i)
      GLL(plane + wv*4096 + i*512 + lane*8, x_lds + wv*4096 + i*512);
  };
  auto stage_a = [&](int s, int buf){
    const int dtdy = s / 3, dz = s % 3;
    const int tap0 = ((dtdy/3)*9 + (dtdy%3)*3 + dz)*3;   // ((dt*3+dy)*3+dz)*3
    const u16* asrc = wp + (size_t)tap0 * 4096;          // 3 taps, 24 KB contiguous
#pragma unroll
    for (int i = 0; i < 6; ++i)
      GLL(asrc + wv*3072 + i*512 + lane*8, a_lds[buf] + wv*3072 + i*512);
  };

  // prologue
  stage_x(0);
  stage_a(0, 0);
  __syncthreads();   // drain: x plane 0 + a slab 0 ready

  for (int s = 0; s < 27; ++s){
    const int dz  = s % 3;
    const int cur = s & 1;
    const bool boundary = (dz == 2);        // next s starts a new (dt,dy)
    if (s + 1 < 27 && !boundary)
      stage_a(s + 1, cur ^ 1);              // async prefetch, overlaps MFMAs below

    // ---- compute slab s: 96 MFMAs
    const u16* ab = a_lds[cur];
#pragma unroll
    for (int dw = 0; dw < 3; ++dw){
      const int ww = (wl + dw + 15) & 15;
      const int wx = ww & 7;
#pragma unroll
      for (int kc = 0; kc < 2; ++kc){
        bf16x8 af[4];
#pragma unroll
        for (int mi = 0; mi < 4; ++mi)
          af[mi] = *(const bf16x8*)(ab + ((dw*2 + kc)*64 + mi*16 + wl)*32 + q*8);
        const int chunk = ((kc*4 + q) ^ wx)*8;
#pragma unroll
        for (int zi = 0; zi < 4; ++zi){
          const int zz = (wv*4 + zi + dz + 15) & 15;
          bf16x8 bf = *(const bf16x8*)(x_lds + (zz*16 + ww)*64 + chunk);
#pragma unroll
          for (int mi = 0; mi < 4; ++mi)
            acc[zi][mi] = __builtin_amdgcn_mfma_f32_16x16x32_bf16(af[mi], bf, acc[zi][mi], 0, 0, 0);
        }
      }
    }

    if (s + 1 >= 27) break;
    if (boundary){
      __syncthreads();                      // compute done: x_lds + both a bufs free
      stage_x(s/3 + 1);
      stage_a(s + 1, cur ^ 1);
      __syncthreads();                      // drain x + a for next iteration
    } else {
      __syncthreads();                      // a slab s+1 visible (vmcnt already ~drained)
    }
  }

  // ---- epilogue: bias + fp32 store
  float bvals[4][4];
#pragma unroll
  for (int mi = 0; mi < 4; ++mi)
#pragma unroll
    for (int r = 0; r < 4; ++r)
      bvals[mi][r] = bias[mi*16 + q*4 + r];

  float* ob = out + (size_t)b*64*65536 + t*4096 + y*256 + wl;
#pragma unroll
  for (int zi = 0; zi < 4; ++zi){
    const int z = wv*4 + zi;
#pragma unroll
    for (int mi = 0; mi < 4; ++mi){
#pragma unroll
      for (int r = 0; r < 4; ++r){
        const int co = mi*16 + q*4 + r;   // C/D: row = quad*4 + reg
        ob[(size_t)co*65536 + z*16] = acc[zi][mi][r] + bvals[mi][r];
      }
    }
  }
}

// ===================== FALLBACK (round-2 proven path) =======================
__global__ void repack_w_kernel(const float* __restrict__ w, u16* __restrict__ wp){
  int idx = blockIdx.x * 256 + threadIdx.x;
  if (idx >= 81*64*64) return;
  int cw  = idx & 31;
  int t1  = idx >> 5;
  int co  = t1 & 63; t1 >>= 6;
  int kc  = t1 & 1;  t1 >>= 1;
  int tap = t1;
  int dw = tap % 3, dz = (tap/3) % 3, dy = (tap/9) % 3, dt = tap/27;
  int ci = kc*32 + cw;
  int in_idx = ((((dt*64 + co)*64 + ci)*3 + dy)*3 + dz)*3 + dw;
  wp[idx] = f2bf(w[in_idx]);
}

__global__ __launch_bounds__(256, 2) void conv4d_mfma_kernel(
    const float* __restrict__ x, const u16* __restrict__ wp,
    const float* __restrict__ bias, float* __restrict__ out)
{
  __shared__ __attribute__((aligned(16))) u16 x_lds[256*72];
  __shared__ __attribute__((aligned(16))) u16 a_lds[3*2*64*32];
  const int bx = blockIdx.x;
  const int y = bx & 15, t = (bx >> 4) & 15, b = bx >> 8;
  const int tid  = threadIdx.x;
  const int lane = tid & 63;
  const int wv   = tid >> 6;
  const int wl   = lane & 15;
  const int q    = lane >> 4;
  floatx4 acc[4][4];
#pragma unroll
  for (int zi = 0; zi < 4; ++zi)
#pragma unroll
    for (int mi = 0; mi < 4; ++mi)
      acc[zi][mi] = (floatx4)0.0f;
  const float* xb = x + (size_t)b * 64 * 65536;
  for (int dt = 0; dt < 3; ++dt){
    const int tt = (t + dt + 15) & 15;
    for (int dy = 0; dy < 3; ++dy){
      const int yy = (y + dy + 15) & 15;
      __syncthreads();
      {
        const float* src = xb + tt*4096 + yy*256 + tid;
#pragma unroll
        for (int oct = 0; oct < 8; ++oct){
          float v[8];
#pragma unroll
          for (int j = 0; j < 8; ++j)
            v[j] = src[(size_t)(oct*8 + j) * 65536];
          short8 vv;
#pragma unroll
          for (int j = 0; j < 8; ++j) vv[j] = (short)f2bf(v[j]);
          *(short8*)(x_lds + tid*72 + oct*8) = vv;
        }
      }
      for (int dz = 0; dz < 3; ++dz){
        const int tap0 = ((dt*3 + dy)*3 + dz)*3;
        __syncthreads();
        {
          const u16* asrc = wp + (size_t)tap0 * 4096;
#pragma unroll
          for (int i = 0; i < 6; ++i){
            int e = (i*256 + tid) * 8;
            *(short8*)(a_lds + e) = *(const short8*)(asrc + e);
          }
        }
        __syncthreads();
#pragma unroll
        for (int dw = 0; dw < 3; ++dw){
          const int ww = (wl + dw + 15) & 15;
#pragma unroll
          for (int kc = 0; kc < 2; ++kc){
            bf16x8 af[4];
#pragma unroll
            for (int mi = 0; mi < 4; ++mi)
              af[mi] = *(const bf16x8*)(a_lds + ((dw*2 + kc)*64 + mi*16 + wl)*32 + q*8);
#pragma unroll
            for (int zi = 0; zi < 4; ++zi){
              const int zz = (wv*4 + zi + dz + 15) & 15;
              bf16x8 bf = *(const bf16x8*)(x_lds + (zz*16 + ww)*72 + kc*32 + q*8);
#pragma unroll
              for (int mi = 0; mi < 4; ++mi)
                acc[zi][mi] = __builtin_amdgcn_mfma_f32_16x16x32_bf16(af[mi], bf, acc[zi][mi], 0, 0, 0);
            }
          }
        }
      }
    }
  }
  float bvals[4][4];
#pragma unroll
  for (int mi = 0; mi < 4; ++mi)
#pragma unroll
    for (int r = 0; r < 4; ++r)
      bvals[mi][r] = bias[mi*16 + q*4 + r];
  float* ob = out + (size_t)b * 64 * 65536 + t*4096 + y*256 + wl;
#pragma unroll
  for (int zi = 0; zi < 4; ++zi){
    const int z = wv*4 + zi;
#pragma unroll
    for (int mi = 0; mi < 4; ++mi){
#pragma unroll
      for (int r = 0; r < 4; ++r){
        const int co = mi*16 + q*4 + r;
        ob[(size_t)co*65536 + z*16] = acc[zi][mi][r] + bvals[mi][r];
      }
    }
  }
}

extern "C" void kernel_launch(void* const* d_in, const int* in_sizes, int n_in,
                              void* d_out, int out_size, void* d_ws, size_t ws_size,
                              hipStream_t stream) {
  const float* x    = (const float*)d_in[0];
  const float* w    = (const float*)d_in[1];
  const float* bias = (const float*)d_in[2];
  float* out = (float*)d_out;

  const size_t xp_bytes = (size_t)1024 * 16384 * 2;   // 33.55 MB bf16 transposed x
  const size_t wp_bytes = 81*64*64*2;                  // 663.5 KB packed weights
  if (ws_size >= xp_bytes + wp_bytes){
    u16* xp = (u16*)d_ws;
    u16* wp = (u16*)((char*)d_ws + xp_bytes);
    prep_kernel<<<1024 + 1296, 256, 0, stream>>>(x, w, xp, wp);
    conv4d_mfma_v4<<<1024, 256, 0, stream>>>(xp, wp, bias, out);
  } else {
    u16* wp = (u16*)d_ws;
    repack_w_kernel<<<1296, 256, 0, stream>>>(w, wp);
    conv4d_mfma_kernel<<<1024, 256, 0, stream>>>(x, wp, bias, out);
  }
}